// Round 6
// baseline (1155.674 us; speedup 1.0000x reference)
//
#include <hip/hip_runtime.h>

typedef __attribute__((ext_vector_type(4))) float fx4;
typedef __attribute__((ext_vector_type(8))) unsigned short u16x8;
typedef __attribute__((ext_vector_type(8))) __bf16 bf16x8;

static __device__ __forceinline__ unsigned short f2bf(float f) {
  unsigned int u = __builtin_bit_cast(unsigned int, f);
  u += 0x7fffu + ((u >> 16) & 1u);          // round-to-nearest-even
  return (unsigned short)(u >> 16);
}
static __device__ __forceinline__ fx4 mfma16(u16x8 a, u16x8 b, fx4 c) {
  return __builtin_amdgcn_mfma_f32_16x16x32_bf16(
      __builtin_bit_cast(bf16x8, a), __builtin_bit_cast(bf16x8, b), c, 0, 0, 0);
}

// XOR swizzles (16B-block granular). Weights are PRE-swizzled in ws by prep,
// so kernels copy them linearly into LDS and read with the same swizzle.
static __device__ __forceinline__ int swz128(int row, int col) {  // [.][128] bf16
  return row * 128 + (col ^ ((row & 7) << 3));
}
static __device__ __forceinline__ int swz32(int row, int col) {   // [.][32] bf16
  return row * 32 + (col ^ (((row >> 1) & 3) << 3));
}

// ---- ws layout (ushort units): weights bf16, [N][Kpad], pre-swizzled ----
#define WT_FE1 0        // [128][32]  (fe_W1, K=18 pad 32)
#define WT_FE2 4096     // [128][128] (fe_W2)
#define WT_EE1 20480    // [128][32]  (ee_W1, K=4 pad 32)
#define WT_EE2 24576    // [128][128] (ee_W2)
#define WT_A   40960    // [128][128] (ie_W1 rows 0..127   : sr_sum)
#define WT_B   57344    // [128][128] (ie_W1 rows 128..255 : node_sum)
#define WT_C   73728    // [128][128] (ie_W1 rows 256..383 : edge_latent)
#define WT_IE2 90112    // [128][128] (ie_W2)
#define WT_TOTAL 106496

__global__ void prep_weights(const float* __restrict__ feW1, const float* __restrict__ feW2,
                             const float* __restrict__ eeW1, const float* __restrict__ eeW2,
                             const float* __restrict__ ieW1, const float* __restrict__ ieW2,
                             unsigned short* __restrict__ wt) {
  int i = blockIdx.x * 256 + threadIdx.x;
  if (i >= WT_TOTAL) return;
  int base, n, k, kpad;
  float val;
  if (i < WT_FE2)      { base = WT_FE1; n = i >> 5; k = i & 31; kpad = 32;
                         val = (k < 18) ? feW1[k * 128 + n] : 0.f; }
  else if (i < WT_EE1) { base = WT_FE2; int j = i - WT_FE2; n = j >> 7; k = j & 127; kpad = 128;
                         val = feW2[k * 128 + n]; }
  else if (i < WT_EE2) { base = WT_EE1; int j = i - WT_EE1; n = j >> 5; k = j & 31; kpad = 32;
                         val = (k < 4) ? eeW1[k * 128 + n] : 0.f; }
  else if (i < WT_A)   { base = WT_EE2; int j = i - WT_EE2; n = j >> 7; k = j & 127; kpad = 128;
                         val = eeW2[k * 128 + n]; }
  else if (i < WT_B)   { base = WT_A;   int j = i - WT_A;   n = j >> 7; k = j & 127; kpad = 128;
                         val = ieW1[k * 128 + n]; }
  else if (i < WT_C)   { base = WT_B;   int j = i - WT_B;   n = j >> 7; k = j & 127; kpad = 128;
                         val = ieW1[(128 + k) * 128 + n]; }
  else if (i < WT_IE2) { base = WT_C;   int j = i - WT_C;   n = j >> 7; k = j & 127; kpad = 128;
                         val = ieW1[(256 + k) * 128 + n]; }
  else                 { base = WT_IE2; int j = i - WT_IE2; n = j >> 7; k = j & 127; kpad = 128;
                         val = ieW2[k * 128 + n]; }
  int dst = (kpad == 32) ? base + n * 32 + (k ^ (((n >> 1) & 3) << 3))
                         : base + n * 128 + (k ^ ((n & 7) << 3));
  wt[dst] = f2bf(val);
}

// 16-row GEMM, A from wave-local LDS arena, B from LDS weights (both swizzled).
template<int KPAD, int KT>
static __device__ __forceinline__ void gemm_lds(const unsigned short* As,
                                                const unsigned short* Ws,
                                                fx4* acc, int l16, int lgr) {
#pragma unroll
  for (int kk = 0; kk < KT; kk++) {
    const int k0 = kk * 32 + lgr * 8;
    u16x8 af = *(const u16x8*)(As + ((KPAD == 32) ? swz32(l16, k0) : swz128(l16, k0)));
#pragma unroll
    for (int nt = 0; nt < 8; nt++) {
      const int n = nt * 16 + l16;
      u16x8 bf = *(const u16x8*)(Ws + ((KPAD == 32) ? swz32(n, k0) : swz128(n, k0)));
      acc[nt] = mfma16(af, bf, acc[nt]);
    }
  }
}

// bias + ReLU -> bf16 store into wave-local [16][128] LDS slice.
static __device__ __forceinline__ void relu_store(fx4* acc, const float* __restrict__ bias,
                                                  unsigned short* dst, int l16, int lgr) {
#pragma unroll
  for (int nt = 0; nt < 8; nt++) {
    const int col = nt * 16 + l16;
    const float b = bias[col];
#pragma unroll
    for (int r = 0; r < 4; r++) {
      float v = acc[nt][r] + b;
      dst[swz128(lgr * 4 + r, col)] = f2bf(v > 0.f ? v : 0.f);
    }
  }
}

// bias add + per-row LayerNorm (normalize only; caller applies g/beta).
static __device__ __forceinline__ void ln_rows(fx4* acc, const float* __restrict__ bias, int l16) {
  float sum[4] = {0, 0, 0, 0}, sq[4] = {0, 0, 0, 0};
#pragma unroll
  for (int nt = 0; nt < 8; nt++) {
    const float b = bias[nt * 16 + l16];
#pragma unroll
    for (int r = 0; r < 4; r++) {
      float v = acc[nt][r] + b; acc[nt][r] = v;
      sum[r] += v; sq[r] += v * v;
    }
  }
#pragma unroll
  for (int r = 0; r < 4; r++) {
    float s_ = sum[r], q_ = sq[r];
#pragma unroll
    for (int m = 1; m < 16; m <<= 1) { s_ += __shfl_xor(s_, m, 64); q_ += __shfl_xor(q_, m, 64); }
    const float mu = s_ * (1.f / 128.f);
    const float rs = rsqrtf(q_ * (1.f / 128.f) - mu * mu + 1e-5f);
#pragma unroll
    for (int nt = 0; nt < 8; nt++) acc[nt][r] = (acc[nt][r] - mu) * rs;
  }
}

// ======================= fe kernel (senders/receivers MLP) =======================
// 512 threads, dyn LDS 80KB: weights 40KB | 8 x (h1 4KB + feat 1KB). 2 blocks/CU.
struct ParamsFE {
  const float* basis[3];
  const float* sv[6]; const float* rv[6];
  const float* b1; const float* b2; const float* g; const float* be;
  const unsigned short* wt;
  unsigned short* msg;   // [E][256] bf16, cols 0..127 = sr_sum (aliases d_out)
  int ntiles;
};

__global__ __launch_bounds__(512) void fe_kernel(ParamsFE p) {
  extern __shared__ unsigned short lds[];  // 40960 ushorts
  const int tid = threadIdx.x;
  const int wave = tid >> 6, lane = tid & 63;
  const int l16 = lane & 15, lgr = lane >> 4;
#pragma unroll
  for (int i = tid * 8; i < 20480; i += 4096)
    *(u16x8*)(lds + i) = *(const u16x8*)(p.wt + WT_FE1 + i);
  const unsigned short* W1 = lds;
  const unsigned short* W2 = lds + 4096;
  unsigned short* h1 = lds + 20480 + wave * 2560;
  unsigned short* feat = h1 + 2048;
  __syncthreads();
  // persistent zeros in feat cols 18..31 (never overwritten)
#pragma unroll
  for (int j = 0; j < 4; j++) { int c = 18 + lgr * 4 + j; if (c < 32) feat[swz32(l16, c)] = 0; }
  const fx4 z4 = {0.f, 0.f, 0.f, 0.f};

  for (int t = blockIdx.x; t < p.ntiles; t += gridDim.x) {
    const int e0 = t * 128 + wave * 16;
    const size_t e = (size_t)(e0 + l16);
    float bx[3][3];
#pragma unroll
    for (int i = 0; i < 3; i++) {
      const float* bp = p.basis[i] + 3 * e;
      bx[i][0] = bp[0]; bx[i][1] = bp[1]; bx[i][2] = bp[2];
    }
    fx4 latS[8];
#pragma unroll
    for (int side = 0; side < 2; side++) {
      const bool isR = (side == 1);
#pragma unroll
      for (int k = 0; k < 6; k++) {
        if ((k & 3) == lgr) {   // compile-time k; exec-masked lanes
          const float* vp = (isR ? p.rv[k] : p.sv[k]) + 3 * e;
          const float v0 = vp[0], v1 = vp[1], v2 = vp[2];
          const float sgn = (isR && k != 3 && k != 5) ? -1.f : 1.f;
#pragma unroll
          for (int i = 0; i < 3; i++) {
            float d = (bx[i][0] * v0 + bx[i][1] * v1 + bx[i][2] * v2) * sgn;
            feat[swz32(l16, k * 3 + i)] = f2bf(d);
          }
        }
      }
      fx4 acc[8];
#pragma unroll
      for (int b = 0; b < 8; b++) acc[b] = z4;
      gemm_lds<32, 1>(feat, W1, acc, l16, lgr);
      relu_store(acc, p.b1, h1, l16, lgr);
#pragma unroll
      for (int b = 0; b < 8; b++) acc[b] = z4;
      gemm_lds<128, 4>(h1, W2, acc, l16, lgr);
      ln_rows(acc, p.b2, l16);
      if (!isR) {
#pragma unroll
        for (int nt = 0; nt < 8; nt++) {
          const int col = nt * 16 + l16;
          const float gg = p.g[col], bb = p.be[col];
#pragma unroll
          for (int r = 0; r < 4; r++) latS[nt][r] = acc[nt][r] * gg + bb;
        }
      } else {
#pragma unroll
        for (int nt = 0; nt < 8; nt++) {
          const int col = nt * 16 + l16;
          const float gg = p.g[col], bb = p.be[col];
#pragma unroll
          for (int r = 0; r < 4; r++)
            p.msg[(size_t)(e0 + lgr * 4 + r) * 256 + col] =
                f2bf(latS[nt][r] + acc[nt][r] * gg + bb);
        }
      }
    }
  }
}

// ======================= ee kernel (edge encoder MLP) =======================
struct ParamsEE {
  const float* dx; const float* attr;
  const float* b1; const float* b2; const float* g; const float* be;
  const unsigned short* wt;
  unsigned short* msg;   // cols 128..255 = edge_latent
  int ntiles;
};

__global__ __launch_bounds__(512) void ee_kernel(ParamsEE p) {
  extern __shared__ unsigned short lds[];  // 40960 ushorts
  const int tid = threadIdx.x;
  const int wave = tid >> 6, lane = tid & 63;
  const int l16 = lane & 15, lgr = lane >> 4;
#pragma unroll
  for (int i = tid * 8; i < 20480; i += 4096)
    *(u16x8*)(lds + i) = *(const u16x8*)(p.wt + WT_EE1 + i);
  const unsigned short* W1 = lds;
  const unsigned short* W2 = lds + 4096;
  unsigned short* h1 = lds + 20480 + wave * 2560;
  unsigned short* feat = h1 + 2048;
  __syncthreads();
  // persistent zeros cols 4..31
#pragma unroll
  for (int j = 0; j < 7; j++) feat[swz32(l16, 4 + lgr * 7 + j)] = 0;
  const fx4 z4 = {0.f, 0.f, 0.f, 0.f};

  for (int t = blockIdx.x; t < p.ntiles; t += gridDim.x) {
    const int e0 = t * 128 + wave * 16;
    const size_t e = (size_t)(e0 + l16);
    if (lgr == 0) {
      float d0 = p.dx[3 * e], d1 = p.dx[3 * e + 1], d2 = p.dx[3 * e + 2];
      feat[swz32(l16, 0)] = f2bf(sqrtf(d0 * d0 + d1 * d1 + d2 * d2));
    } else {
      feat[swz32(l16, lgr)] = f2bf(p.attr[3 * e + (lgr - 1)]);
    }
    fx4 acc[8];
#pragma unroll
    for (int b = 0; b < 8; b++) acc[b] = z4;
    gemm_lds<32, 1>(feat, W1, acc, l16, lgr);
    relu_store(acc, p.b1, h1, l16, lgr);
#pragma unroll
    for (int b = 0; b < 8; b++) acc[b] = z4;
    gemm_lds<128, 4>(h1, W2, acc, l16, lgr);
    ln_rows(acc, p.b2, l16);
#pragma unroll
    for (int nt = 0; nt < 8; nt++) {
      const int col = nt * 16 + l16;
      const float gg = p.g[col], bb = p.be[col];
#pragma unroll
      for (int r = 0; r < 4; r++)
        p.msg[(size_t)(e0 + lgr * 4 + r) * 256 + 128 + col] =
            f2bf(acc[nt][r] * gg + bb);
    }
  }
}

// ======================= ie1: 3 GEMMs (K=128) + ReLU -> h1 (msg cols 0..127) ====
// 1024 threads, dyn LDS 96KB weights only. 1 block/CU = 16 waves = 50% occ.
// A-operands read straight from global (msg rows / node rows) in fragment layout.
struct ParamsIE1 {
  const int* eidx;
  const float* nl;
  const float* b1;
  const unsigned short* wt;
  unsigned short* msg;
  int E; int ntiles;
};

__global__ __launch_bounds__(1024) void ie1_kernel(ParamsIE1 p) {
  extern __shared__ unsigned short dyn[];  // WA|WB|WC = 49152 ushorts
  const int tid = threadIdx.x;
  const int wave = tid >> 6, lane = tid & 63;
  const int l16 = lane & 15, lgr = lane >> 4;
#pragma unroll
  for (int i = tid * 8; i < 49152; i += 8192)
    *(u16x8*)(dyn + i) = *(const u16x8*)(p.wt + WT_A + i);
  const unsigned short* WA = dyn;
  const unsigned short* WB = dyn + 16384;
  const unsigned short* WC = dyn + 32768;
  __syncthreads();
  const fx4 z4 = {0.f, 0.f, 0.f, 0.f};

  for (int t = blockIdx.x; t < p.ntiles; t += gridDim.x) {
    const int e0 = t * 256 + wave * 16;
    const size_t e = (size_t)(e0 + l16);
    const int sidx = p.eidx[e];
    const int ridx = p.eidx[(size_t)p.E + e];
    const unsigned short* mrow = p.msg + e * 256;
    const float* ns = p.nl + (size_t)sidx * 128;
    const float* nr = p.nl + (size_t)ridx * 128;
    fx4 acc[8];
#pragma unroll
    for (int b = 0; b < 8; b++) acc[b] = z4;
    // node chunks first (longest-latency gathers issue early)
#pragma unroll
    for (int c = 0; c < 4; c++) {
      const int k0 = c * 32 + lgr * 8;
      fx4 a0 = *(const fx4*)(ns + k0), a1 = *(const fx4*)(ns + k0 + 4);
      fx4 b0 = *(const fx4*)(nr + k0), b1 = *(const fx4*)(nr + k0 + 4);
      u16x8 af;
#pragma unroll
      for (int j = 0; j < 4; j++) { af[j] = f2bf(a0[j] + b0[j]); af[4 + j] = f2bf(a1[j] + b1[j]); }
#pragma unroll
      for (int nt = 0; nt < 8; nt++) {
        u16x8 bf = *(const u16x8*)(WB + swz128(nt * 16 + l16, k0));
        acc[nt] = mfma16(af, bf, acc[nt]);
      }
    }
    // sr chunks (msg cols 0..127, linear layout)
#pragma unroll
    for (int c = 0; c < 4; c++) {
      const int k0 = c * 32 + lgr * 8;
      u16x8 af = *(const u16x8*)(mrow + k0);
#pragma unroll
      for (int nt = 0; nt < 8; nt++) {
        u16x8 bf = *(const u16x8*)(WA + swz128(nt * 16 + l16, k0));
        acc[nt] = mfma16(af, bf, acc[nt]);
      }
    }
    // el chunks (msg cols 128..255)
#pragma unroll
    for (int c = 0; c < 4; c++) {
      const int k0 = c * 32 + lgr * 8;
      u16x8 af = *(const u16x8*)(mrow + 128 + k0);
#pragma unroll
      for (int nt = 0; nt < 8; nt++) {
        u16x8 bf = *(const u16x8*)(WC + swz128(nt * 16 + l16, k0));
        acc[nt] = mfma16(af, bf, acc[nt]);
      }
    }
    // ReLU -> h1 bf16, overwrite msg cols 0..127 (this wave's rows only; sr
    // for these rows was fully consumed above).
#pragma unroll
    for (int nt = 0; nt < 8; nt++) {
      const int col = nt * 16 + l16;
      const float b = p.b1[col];
#pragma unroll
      for (int r = 0; r < 4; r++) {
        float v = acc[nt][r] + b;
        p.msg[(size_t)(e0 + lgr * 4 + r) * 256 + col] = f2bf(v > 0.f ? v : 0.f);
      }
    }
  }
}

// ======================= ie2: W2-GEMM + LN -> out (f32) =======================
// 512 threads, static 32KB LDS (W2). A (h1) read from global msg cols 0..127.
struct ParamsIE2 {
  const float* b2; const float* g; const float* be;
  const unsigned short* wt;
  const unsigned short* msg;
  float* out;
  int ntiles;
};

__global__ __launch_bounds__(512) void ie2_kernel(ParamsIE2 p) {
  __shared__ unsigned short W2[16384];
  const int tid = threadIdx.x;
  const int wave = tid >> 6, lane = tid & 63;
  const int l16 = lane & 15, lgr = lane >> 4;
#pragma unroll
  for (int i = tid * 8; i < 16384; i += 4096)
    *(u16x8*)(W2 + i) = *(const u16x8*)(p.wt + WT_IE2 + i);
  __syncthreads();
  const fx4 z4 = {0.f, 0.f, 0.f, 0.f};

  for (int t = blockIdx.x; t < p.ntiles; t += gridDim.x) {
    const int e0 = t * 128 + wave * 16;
    const size_t e = (size_t)(e0 + l16);
    const unsigned short* mrow = p.msg + e * 256;
    fx4 acc[8];
#pragma unroll
    for (int b = 0; b < 8; b++) acc[b] = z4;
#pragma unroll
    for (int c = 0; c < 4; c++) {
      const int k0 = c * 32 + lgr * 8;
      u16x8 af = *(const u16x8*)(mrow + k0);
#pragma unroll
      for (int nt = 0; nt < 8; nt++) {
        u16x8 bf = *(const u16x8*)(W2 + swz128(nt * 16 + l16, k0));
        acc[nt] = mfma16(af, bf, acc[nt]);
      }
    }
    ln_rows(acc, p.b2, l16);
#pragma unroll
    for (int nt = 0; nt < 8; nt++) {
      const int col = nt * 16 + l16;
      const float gg = p.g[col], bb = p.be[col];
#pragma unroll
      for (int r = 0; r < 4; r++)
        p.out[(size_t)(e0 + lgr * 4 + r) * 128 + col] = acc[nt][r] * gg + bb;
    }
  }
}

extern "C" void kernel_launch(void* const* d_in, const int* in_sizes, int n_in,
                              void* d_out, int out_size, void* d_ws, size_t ws_size,
                              hipStream_t stream) {
  (void)n_in; (void)out_size;
  const int E = in_sizes[1] / 3;  // edge_dx_ is [E,3]
  unsigned short* wt = reinterpret_cast<unsigned short*>(d_ws);
  if (ws_size < (size_t)WT_TOTAL * sizeof(unsigned short)) return;

  prep_weights<<<(WT_TOTAL + 255) / 256, 256, 0, stream>>>(
      (const float*)d_in[19], (const float*)d_in[21],
      (const float*)d_in[25], (const float*)d_in[27],
      (const float*)d_in[31], (const float*)d_in[33], wt);

  unsigned short* msg = (unsigned short*)d_out;  // [E][256] bf16 staging inside d_out

  hipFuncSetAttribute((const void*)fe_kernel,
                      hipFuncAttributeMaxDynamicSharedMemorySize, 81920);
  hipFuncSetAttribute((const void*)ee_kernel,
                      hipFuncAttributeMaxDynamicSharedMemorySize, 81920);
  hipFuncSetAttribute((const void*)ie1_kernel,
                      hipFuncAttributeMaxDynamicSharedMemorySize, 98304);

  ParamsFE pf;
  for (int i = 0; i < 3; i++) pf.basis[i] = (const float*)d_in[3 + i];
  for (int k = 0; k < 6; k++) { pf.sv[k] = (const float*)d_in[6 + k]; pf.rv[k] = (const float*)d_in[12 + k]; }
  pf.b1 = (const float*)d_in[20]; pf.b2 = (const float*)d_in[22];
  pf.g  = (const float*)d_in[23]; pf.be = (const float*)d_in[24];
  pf.wt = wt; pf.msg = msg; pf.ntiles = E / 128;
  fe_kernel<<<512, 512, 81920, stream>>>(pf);

  ParamsEE pe;
  pe.dx = (const float*)d_in[1]; pe.attr = (const float*)d_in[2];
  pe.b1 = (const float*)d_in[26]; pe.b2 = (const float*)d_in[28];
  pe.g  = (const float*)d_in[29]; pe.be = (const float*)d_in[30];
  pe.wt = wt; pe.msg = msg; pe.ntiles = E / 128;
  ee_kernel<<<512, 512, 81920, stream>>>(pe);

  ParamsIE1 p1;
  p1.eidx = (const int*)d_in[0];
  p1.nl = (const float*)d_in[18];
  p1.b1 = (const float*)d_in[32];
  p1.wt = wt; p1.msg = msg; p1.E = E; p1.ntiles = E / 256;
  ie1_kernel<<<256, 1024, 98304, stream>>>(p1);

  ParamsIE2 p2;
  p2.b2 = (const float*)d_in[34];
  p2.g  = (const float*)d_in[35]; p2.be = (const float*)d_in[36];
  p2.wt = wt; p2.msg = msg; p2.out = (float*)d_out;
  p2.ntiles = E / 128;
  ie2_kernel<<<512, 512, 0, stream>>>(p2);
}

// Round 7
// 549.475 us; speedup vs baseline: 2.1032x; 2.1032x over previous
//
#include <hip/hip_runtime.h>

typedef __attribute__((ext_vector_type(4))) float fx4;
typedef __attribute__((ext_vector_type(8))) unsigned short u16x8;
typedef __attribute__((ext_vector_type(8))) __bf16 bf16x8;

static __device__ __forceinline__ unsigned short f2bf(float f) {
  unsigned int u = __builtin_bit_cast(unsigned int, f);
  u += 0x7fffu + ((u >> 16) & 1u);          // round-to-nearest-even
  return (unsigned short)(u >> 16);
}
static __device__ __forceinline__ fx4 mfma16(u16x8 a, u16x8 b, fx4 c) {
  return __builtin_amdgcn_mfma_f32_16x16x32_bf16(
      __builtin_bit_cast(bf16x8, a), __builtin_bit_cast(bf16x8, b), c, 0, 0, 0);
}

// XOR swizzles (16B-block granular). Weights are PRE-swizzled in ws by prep,
// so kernels copy them linearly into LDS and read with the same swizzle.
static __device__ __forceinline__ int swz128(int row, int col) {  // [.][128] bf16
  return row * 128 + (col ^ ((row & 7) << 3));
}
static __device__ __forceinline__ int swz32(int row, int col) {   // [.][32] bf16
  return row * 32 + (col ^ (((row >> 1) & 3) << 3));
}

// ---- ws layout (ushort units): weights bf16, [N][Kpad], pre-swizzled ----
#define WT_FE1 0        // [128][32]  (fe_W1, K=18 pad 32)
#define WT_FE2 4096     // [128][128] (fe_W2)
#define WT_EE1 20480    // [128][32]  (ee_W1, K=4 pad 32)
#define WT_EE2 24576    // [128][128] (ee_W2)
#define WT_A   40960    // [128][128] (ie_W1 rows 0..127   : sr_sum)
#define WT_B   57344    // [128][128] (ie_W1 rows 128..255 : node_sum)
#define WT_C   73728    // [128][128] (ie_W1 rows 256..383 : edge_latent)
#define WT_IE2 90112    // [128][128] (ie_W2)
#define WT_TOTAL 106496

__global__ void prep_weights(const float* __restrict__ feW1, const float* __restrict__ feW2,
                             const float* __restrict__ eeW1, const float* __restrict__ eeW2,
                             const float* __restrict__ ieW1, const float* __restrict__ ieW2,
                             unsigned short* __restrict__ wt) {
  int i = blockIdx.x * 256 + threadIdx.x;
  if (i >= WT_TOTAL) return;
  int base, n, k, kpad;
  float val;
  if (i < WT_FE2)      { base = WT_FE1; n = i >> 5; k = i & 31; kpad = 32;
                         val = (k < 18) ? feW1[k * 128 + n] : 0.f; }
  else if (i < WT_EE1) { base = WT_FE2; int j = i - WT_FE2; n = j >> 7; k = j & 127; kpad = 128;
                         val = feW2[k * 128 + n]; }
  else if (i < WT_EE2) { base = WT_EE1; int j = i - WT_EE1; n = j >> 5; k = j & 31; kpad = 32;
                         val = (k < 4) ? eeW1[k * 128 + n] : 0.f; }
  else if (i < WT_A)   { base = WT_EE2; int j = i - WT_EE2; n = j >> 7; k = j & 127; kpad = 128;
                         val = eeW2[k * 128 + n]; }
  else if (i < WT_B)   { base = WT_A;   int j = i - WT_A;   n = j >> 7; k = j & 127; kpad = 128;
                         val = ieW1[k * 128 + n]; }
  else if (i < WT_C)   { base = WT_B;   int j = i - WT_B;   n = j >> 7; k = j & 127; kpad = 128;
                         val = ieW1[(128 + k) * 128 + n]; }
  else if (i < WT_IE2) { base = WT_C;   int j = i - WT_C;   n = j >> 7; k = j & 127; kpad = 128;
                         val = ieW1[(256 + k) * 128 + n]; }
  else                 { base = WT_IE2; int j = i - WT_IE2; n = j >> 7; k = j & 127; kpad = 128;
                         val = ieW2[k * 128 + n]; }
  int dst = (kpad == 32) ? base + n * 32 + (k ^ (((n >> 1) & 3) << 3))
                         : base + n * 128 + (k ^ ((n & 7) << 3));
  wt[dst] = f2bf(val);
}

// 16-row GEMM, A from wave-local LDS arena, B from LDS (or global) weights,
// both swizzled.
template<int KPAD, int KT>
static __device__ __forceinline__ void gemm_lds(const unsigned short* As,
                                                const unsigned short* Ws,
                                                fx4* acc, int l16, int lgr) {
#pragma unroll
  for (int kk = 0; kk < KT; kk++) {
    const int k0 = kk * 32 + lgr * 8;
    u16x8 af = *(const u16x8*)(As + ((KPAD == 32) ? swz32(l16, k0) : swz128(l16, k0)));
#pragma unroll
    for (int nt = 0; nt < 8; nt++) {
      const int n = nt * 16 + l16;
      u16x8 bf = *(const u16x8*)(Ws + ((KPAD == 32) ? swz32(n, k0) : swz128(n, k0)));
      acc[nt] = mfma16(af, bf, acc[nt]);
    }
  }
}

// bias + ReLU -> bf16 store into wave-local [16][128] LDS slice.
static __device__ __forceinline__ void relu_store(fx4* acc, const float* __restrict__ bias,
                                                  unsigned short* dst, int l16, int lgr) {
#pragma unroll
  for (int nt = 0; nt < 8; nt++) {
    const int col = nt * 16 + l16;
    const float b = bias[col];
#pragma unroll
    for (int r = 0; r < 4; r++) {
      float v = acc[nt][r] + b;
      dst[swz128(lgr * 4 + r, col)] = f2bf(v > 0.f ? v : 0.f);
    }
  }
}

// bias add + per-row LayerNorm (normalize only; caller applies g/beta).
static __device__ __forceinline__ void ln_rows(fx4* acc, const float* __restrict__ bias, int l16) {
  float sum[4] = {0, 0, 0, 0}, sq[4] = {0, 0, 0, 0};
#pragma unroll
  for (int nt = 0; nt < 8; nt++) {
    const float b = bias[nt * 16 + l16];
#pragma unroll
    for (int r = 0; r < 4; r++) {
      float v = acc[nt][r] + b; acc[nt][r] = v;
      sum[r] += v; sq[r] += v * v;
    }
  }
#pragma unroll
  for (int r = 0; r < 4; r++) {
    float s_ = sum[r], q_ = sq[r];
#pragma unroll
    for (int m = 1; m < 16; m <<= 1) { s_ += __shfl_xor(s_, m, 64); q_ += __shfl_xor(q_, m, 64); }
    const float mu = s_ * (1.f / 128.f);
    const float rs = rsqrtf(q_ * (1.f / 128.f) - mu * mu + 1e-5f);
#pragma unroll
    for (int nt = 0; nt < 8; nt++) acc[nt][r] = (acc[nt][r] - mu) * rs;
  }
}

// ======================= fe kernel (senders/receivers MLP) =======================
// 512 threads, dyn LDS 80KB: weights 40KB | 8 x (h1 4KB + feat 1KB). 2 blocks/CU.
struct ParamsFE {
  const float* basis[3];
  const float* sv[6]; const float* rv[6];
  const float* b1; const float* b2; const float* g; const float* be;
  const unsigned short* wt;
  unsigned short* msg;   // [E][256] bf16, cols 0..127 = sr_sum (aliases d_out)
  int ntiles;
};

__global__ __launch_bounds__(512) void fe_kernel(ParamsFE p) {
  extern __shared__ unsigned short lds[];  // 40960 ushorts
  const int tid = threadIdx.x;
  const int wave = tid >> 6, lane = tid & 63;
  const int l16 = lane & 15, lgr = lane >> 4;
#pragma unroll
  for (int i = tid * 8; i < 20480; i += 4096)
    *(u16x8*)(lds + i) = *(const u16x8*)(p.wt + WT_FE1 + i);
  const unsigned short* W1 = lds;
  const unsigned short* W2 = lds + 4096;
  unsigned short* h1 = lds + 20480 + wave * 2560;
  unsigned short* feat = h1 + 2048;
  __syncthreads();
  // persistent zeros in feat cols 18..31 (never overwritten)
#pragma unroll
  for (int j = 0; j < 4; j++) { int c = 18 + lgr * 4 + j; if (c < 32) feat[swz32(l16, c)] = 0; }
  const fx4 z4 = {0.f, 0.f, 0.f, 0.f};

  for (int t = blockIdx.x; t < p.ntiles; t += gridDim.x) {
    const int e0 = t * 128 + wave * 16;
    const size_t e = (size_t)(e0 + l16);
    float bx[3][3];
#pragma unroll
    for (int i = 0; i < 3; i++) {
      const float* bp = p.basis[i] + 3 * e;
      bx[i][0] = bp[0]; bx[i][1] = bp[1]; bx[i][2] = bp[2];
    }
    fx4 latS[8];
#pragma unroll
    for (int side = 0; side < 2; side++) {
      const bool isR = (side == 1);
#pragma unroll
      for (int k = 0; k < 6; k++) {
        if ((k & 3) == lgr) {   // compile-time k; exec-masked lanes
          const float* vp = (isR ? p.rv[k] : p.sv[k]) + 3 * e;
          const float v0 = vp[0], v1 = vp[1], v2 = vp[2];
          const float sgn = (isR && k != 3 && k != 5) ? -1.f : 1.f;
#pragma unroll
          for (int i = 0; i < 3; i++) {
            float d = (bx[i][0] * v0 + bx[i][1] * v1 + bx[i][2] * v2) * sgn;
            feat[swz32(l16, k * 3 + i)] = f2bf(d);
          }
        }
      }
      fx4 acc[8];
#pragma unroll
      for (int b = 0; b < 8; b++) acc[b] = z4;
      gemm_lds<32, 1>(feat, W1, acc, l16, lgr);
      relu_store(acc, p.b1, h1, l16, lgr);
#pragma unroll
      for (int b = 0; b < 8; b++) acc[b] = z4;
      gemm_lds<128, 4>(h1, W2, acc, l16, lgr);
      ln_rows(acc, p.b2, l16);
      if (!isR) {
#pragma unroll
        for (int nt = 0; nt < 8; nt++) {
          const int col = nt * 16 + l16;
          const float gg = p.g[col], bb = p.be[col];
#pragma unroll
          for (int r = 0; r < 4; r++) latS[nt][r] = acc[nt][r] * gg + bb;
        }
      } else {
#pragma unroll
        for (int nt = 0; nt < 8; nt++) {
          const int col = nt * 16 + l16;
          const float gg = p.g[col], bb = p.be[col];
#pragma unroll
          for (int r = 0; r < 4; r++)
            p.msg[(size_t)(e0 + lgr * 4 + r) * 256 + col] =
                f2bf(latS[nt][r] + acc[nt][r] * gg + bb);
        }
      }
    }
  }
}

// ======================= ee kernel (edge encoder MLP) =======================
struct ParamsEE {
  const float* dx; const float* attr;
  const float* b1; const float* b2; const float* g; const float* be;
  const unsigned short* wt;
  unsigned short* msg;   // cols 128..255 = edge_latent
  int ntiles;
};

__global__ __launch_bounds__(512) void ee_kernel(ParamsEE p) {
  extern __shared__ unsigned short lds[];  // 40960 ushorts
  const int tid = threadIdx.x;
  const int wave = tid >> 6, lane = tid & 63;
  const int l16 = lane & 15, lgr = lane >> 4;
#pragma unroll
  for (int i = tid * 8; i < 20480; i += 4096)
    *(u16x8*)(lds + i) = *(const u16x8*)(p.wt + WT_EE1 + i);
  const unsigned short* W1 = lds;
  const unsigned short* W2 = lds + 4096;
  unsigned short* h1 = lds + 20480 + wave * 2560;
  unsigned short* feat = h1 + 2048;
  __syncthreads();
  // persistent zeros cols 4..31
#pragma unroll
  for (int j = 0; j < 7; j++) feat[swz32(l16, 4 + lgr * 7 + j)] = 0;
  const fx4 z4 = {0.f, 0.f, 0.f, 0.f};

  for (int t = blockIdx.x; t < p.ntiles; t += gridDim.x) {
    const int e0 = t * 128 + wave * 16;
    const size_t e = (size_t)(e0 + l16);
    if (lgr == 0) {
      float d0 = p.dx[3 * e], d1 = p.dx[3 * e + 1], d2 = p.dx[3 * e + 2];
      feat[swz32(l16, 0)] = f2bf(sqrtf(d0 * d0 + d1 * d1 + d2 * d2));
    } else {
      feat[swz32(l16, lgr)] = f2bf(p.attr[3 * e + (lgr - 1)]);
    }
    fx4 acc[8];
#pragma unroll
    for (int b = 0; b < 8; b++) acc[b] = z4;
    gemm_lds<32, 1>(feat, W1, acc, l16, lgr);
    relu_store(acc, p.b1, h1, l16, lgr);
#pragma unroll
    for (int b = 0; b < 8; b++) acc[b] = z4;
    gemm_lds<128, 4>(h1, W2, acc, l16, lgr);
    ln_rows(acc, p.b2, l16);
#pragma unroll
    for (int nt = 0; nt < 8; nt++) {
      const int col = nt * 16 + l16;
      const float gg = p.g[col], bb = p.be[col];
#pragma unroll
      for (int r = 0; r < 4; r++)
        p.msg[(size_t)(e0 + lgr * 4 + r) * 256 + 128 + col] =
            f2bf(acc[nt][r] * gg + bb);
    }
  }
}

// ============ ie kernel (fused layer1 + layer2 + LN -> out f32) ============
// 512 threads (8 waves -> VGPR budget 256, no spill; NEVER 1024: that caps
// VGPR at 64 and spills MFMA accumulators to scratch, R6 lesson).
// Dyn LDS 128KB: WA|WB|WC 96KB + 8 x 4KB per-wave h1 arenas. 1 block/CU.
// W2 (32KB) is read from GLOBAL per-fragment: it fits L1 entirely.
struct ParamsIE {
  const int* eidx;
  const float* nl;
  const float* b1; const float* b2; const float* g; const float* be;
  const unsigned short* wt;
  const unsigned short* msg;  // aliases out (rows consumed before overwrite)
  float* out;
  int E; int ntiles;
};

__global__ __launch_bounds__(512) void ie_kernel(ParamsIE p) {
  extern __shared__ unsigned short dyn[];  // 49152 weights + 8*2048 arenas
  const int tid = threadIdx.x;
  const int wave = tid >> 6, lane = tid & 63;
  const int l16 = lane & 15, lgr = lane >> 4;
#pragma unroll
  for (int i = tid * 8; i < 49152; i += 4096)
    *(u16x8*)(dyn + i) = *(const u16x8*)(p.wt + WT_A + i);
  const unsigned short* WA = dyn;
  const unsigned short* WB = dyn + 16384;
  const unsigned short* WC = dyn + 32768;
  unsigned short* h1 = dyn + 49152 + wave * 2048;
  __syncthreads();
  const fx4 z4 = {0.f, 0.f, 0.f, 0.f};

  for (int t = blockIdx.x; t < p.ntiles; t += gridDim.x) {
    const int e0 = t * 128 + wave * 16;
    const size_t e = (size_t)(e0 + l16);
    const int sidx = p.eidx[e];
    const int ridx = p.eidx[(size_t)p.E + e];
    const unsigned short* mrow = p.msg + e * 256;
    const float* ns = p.nl + (size_t)sidx * 128;
    const float* nr = p.nl + (size_t)ridx * 128;
    fx4 acc[8];
#pragma unroll
    for (int b = 0; b < 8; b++) acc[b] = z4;
    // node chunks first (longest-latency gathers issue early)
#pragma unroll
    for (int c = 0; c < 4; c++) {
      const int k0 = c * 32 + lgr * 8;
      fx4 a0 = *(const fx4*)(ns + k0), a1 = *(const fx4*)(ns + k0 + 4);
      fx4 b0 = *(const fx4*)(nr + k0), b1 = *(const fx4*)(nr + k0 + 4);
      u16x8 af;
#pragma unroll
      for (int j = 0; j < 4; j++) { af[j] = f2bf(a0[j] + b0[j]); af[4 + j] = f2bf(a1[j] + b1[j]); }
#pragma unroll
      for (int nt = 0; nt < 8; nt++) {
        u16x8 bf = *(const u16x8*)(WB + swz128(nt * 16 + l16, k0));
        acc[nt] = mfma16(af, bf, acc[nt]);
      }
    }
    // sr chunks (msg cols 0..127, linear layout)
#pragma unroll
    for (int c = 0; c < 4; c++) {
      const int k0 = c * 32 + lgr * 8;
      u16x8 af = *(const u16x8*)(mrow + k0);
#pragma unroll
      for (int nt = 0; nt < 8; nt++) {
        u16x8 bf = *(const u16x8*)(WA + swz128(nt * 16 + l16, k0));
        acc[nt] = mfma16(af, bf, acc[nt]);
      }
    }
    // el chunks (msg cols 128..255)
#pragma unroll
    for (int c = 0; c < 4; c++) {
      const int k0 = c * 32 + lgr * 8;
      u16x8 af = *(const u16x8*)(mrow + 128 + k0);
#pragma unroll
      for (int nt = 0; nt < 8; nt++) {
        u16x8 bf = *(const u16x8*)(WC + swz128(nt * 16 + l16, k0));
        acc[nt] = mfma16(af, bf, acc[nt]);
      }
    }
    // ReLU -> per-wave LDS arena
    relu_store(acc, p.b1, h1, l16, lgr);
    // layer 2: A from arena (LDS), B from global W2 (L1-resident 32KB)
#pragma unroll
    for (int b = 0; b < 8; b++) acc[b] = z4;
    gemm_lds<128, 4>(h1, p.wt + WT_IE2, acc, l16, lgr);
    ln_rows(acc, p.b2, l16);
#pragma unroll
    for (int nt = 0; nt < 8; nt++) {
      const int col = nt * 16 + l16;
      const float gg = p.g[col], bb = p.be[col];
#pragma unroll
      for (int r = 0; r < 4; r++)
        p.out[(size_t)(e0 + lgr * 4 + r) * 128 + col] = acc[nt][r] * gg + bb;
    }
  }
}

extern "C" void kernel_launch(void* const* d_in, const int* in_sizes, int n_in,
                              void* d_out, int out_size, void* d_ws, size_t ws_size,
                              hipStream_t stream) {
  (void)n_in; (void)out_size;
  const int E = in_sizes[1] / 3;  // edge_dx_ is [E,3]
  unsigned short* wt = reinterpret_cast<unsigned short*>(d_ws);
  if (ws_size < (size_t)WT_TOTAL * sizeof(unsigned short)) return;

  prep_weights<<<(WT_TOTAL + 255) / 256, 256, 0, stream>>>(
      (const float*)d_in[19], (const float*)d_in[21],
      (const float*)d_in[25], (const float*)d_in[27],
      (const float*)d_in[31], (const float*)d_in[33], wt);

  unsigned short* msg = (unsigned short*)d_out;  // [E][256] bf16 staging inside d_out

  hipFuncSetAttribute((const void*)fe_kernel,
                      hipFuncAttributeMaxDynamicSharedMemorySize, 81920);
  hipFuncSetAttribute((const void*)ee_kernel,
                      hipFuncAttributeMaxDynamicSharedMemorySize, 81920);
  hipFuncSetAttribute((const void*)ie_kernel,
                      hipFuncAttributeMaxDynamicSharedMemorySize, 131072);

  ParamsFE pf;
  for (int i = 0; i < 3; i++) pf.basis[i] = (const float*)d_in[3 + i];
  for (int k = 0; k < 6; k++) { pf.sv[k] = (const float*)d_in[6 + k]; pf.rv[k] = (const float*)d_in[12 + k]; }
  pf.b1 = (const float*)d_in[20]; pf.b2 = (const float*)d_in[22];
  pf.g  = (const float*)d_in[23]; pf.be = (const float*)d_in[24];
  pf.wt = wt; pf.msg = msg; pf.ntiles = E / 128;
  fe_kernel<<<512, 512, 81920, stream>>>(pf);

  ParamsEE pe;
  pe.dx = (const float*)d_in[1]; pe.attr = (const float*)d_in[2];
  pe.b1 = (const float*)d_in[26]; pe.b2 = (const float*)d_in[28];
  pe.g  = (const float*)d_in[29]; pe.be = (const float*)d_in[30];
  pe.wt = wt; pe.msg = msg; pe.ntiles = E / 128;
  ee_kernel<<<512, 512, 81920, stream>>>(pe);

  ParamsIE pi;
  pi.eidx = (const int*)d_in[0];
  pi.nl = (const float*)d_in[18];
  pi.b1 = (const float*)d_in[32]; pi.b2 = (const float*)d_in[34];
  pi.g  = (const float*)d_in[35]; pi.be = (const float*)d_in[36];
  pi.wt = wt; pi.msg = msg; pi.out = (float*)d_out;
  pi.E = E; pi.ntiles = E / 128;
  ie_kernel<<<256, 512, 131072, stream>>>(pi);
}